// Round 10
// baseline (2425.579 us; speedup 1.0000x reference)
//
#include <hip/hip_runtime.h>
#include <math.h>

// ---------------------------------------------------------------------------
// GraphConvNetLSTM: GCN (3 layers, reassociated Ahat@(H@W.T)) + 3-layer bidir
// LSTM. k_enc: 7 waves (6 compute = layer x dir, 1 staging) pipelined over
// 256-step chunks via double-buffered LDS. k_dec: wave 0 = serial recurrence
// (h2 -> LDS ring), wave 1 = sigmoid head one phase behind. Packed fp32 dots;
// cell tanh via rational CF approx (1 rcp, no exp on that chain segment);
// c carried UNSCALED. DPP quad-gather, SGPR broadcasts.
// ---------------------------------------------------------------------------

#define GCNW 10
#define LOG2E 1.4426950408889634f
#define CHK  256     // encode pipeline chunk (timesteps)
#define CROW 12      // padded LDS row stride (floats)

typedef float v2f __attribute__((ext_vector_type(2)));

__device__ __forceinline__ v2f pkfma(v2f a, v2f b, v2f c) {
#if __has_builtin(__builtin_elementwise_fma)
    return __builtin_elementwise_fma(a, b, c);
#else
    v2f r; r.x = fmaf(a.x, b.x, c.x); r.y = fmaf(a.y, b.y, c.y); return r;
#endif
}

__device__ __forceinline__ float rl(float v, int l) {
    return __int_as_float(__builtin_amdgcn_readlane(__float_as_int(v), l));
}
__device__ __forceinline__ float frcp(float x) { return __builtin_amdgcn_rcpf(x); }

#if __has_builtin(__builtin_amdgcn_exp2f)
__device__ __forceinline__ float fexp2(float x) { return __builtin_amdgcn_exp2f(x); }
#else
__device__ __forceinline__ float fexp2(float x) { return __expf(x * 0.6931471805599453f); }
#endif

template <int L>
__device__ __forceinline__ float qb(float v) {
    constexpr int ctrl = L | (L << 2) | (L << 4) | (L << 6);
    int r = __builtin_amdgcn_update_dpp(0, __float_as_int(v), ctrl, 0xF, 0xF, true);
    return __int_as_float(r);
}

__device__ __forceinline__ float selu_f(float x) {
    const float lam = 1.0507009873554805f;
    const float la  = 1.7580993408473766f;
    return x > 0.f ? lam * x : la * (__expf(x) - 1.f);
}

// ---- k_pre: blocks [0,n) rowsum->s ; blocks [n,2n) Y0t[o][i] = X[i]@W0.T ---
__global__ __launch_bounds__(256) void k_pre(const float* __restrict__ A,
                                             const float* __restrict__ X,
                                             const float* __restrict__ W0,
                                             float* __restrict__ s,
                                             float* __restrict__ Y0t,
                                             int n, int feat) {
    const int b   = blockIdx.x;
    const int tid = threadIdx.x;
    if (b < n) {
        __shared__ float red[256];
        const float4* row4 = (const float4*)(A + (size_t)b * n);
        float acc = 0.f;
        for (int j = tid; j < n / 4; j += 256) {
            float4 a = row4[j];
            acc += (a.x + a.y) + (a.z + a.w);
        }
        red[tid] = acc; __syncthreads();
        #pragma unroll
        for (int w = 128; w > 0; w >>= 1) {
            if (tid < w) red[tid] += red[tid + w];
            __syncthreads();
        }
        if (tid == 0) {
            float deg = red[0];
            s[b] = (deg > 0.f) ? rsqrtf(deg) : 0.f;
        }
    } else {
        const int i = b - n;
        float acc[GCNW];
        #pragma unroll
        for (int o = 0; o < GCNW; ++o) acc[o] = 0.f;
        const float* xr = X + (size_t)i * feat;
        for (int j = tid; j < feat; j += 256) {
            float xv = xr[j];
            #pragma unroll
            for (int o = 0; o < GCNW; ++o) acc[o] = fmaf(xv, W0[o * feat + j], acc[o]);
        }
        #pragma unroll
        for (int o = 0; o < GCNW; ++o) {
            float v = acc[o];
            #pragma unroll
            for (int off = 32; off > 0; off >>= 1) v += __shfl_xor(v, off);
            acc[o] = v;
        }
        __shared__ float part[4][GCNW];
        const int wv = tid >> 6, ln = tid & 63;
        if (ln == 0) {
            #pragma unroll
            for (int o = 0; o < GCNW; ++o) part[wv][o] = acc[o];
        }
        __syncthreads();
        if (tid < GCNW)
            Y0t[(size_t)tid * n + i] =
                part[0][tid] + part[1][tid] + part[2][tid] + part[3][tid];
    }
}

// ---- k_ap: z = selu(s_i*(sum_j A_ij s_j Y_j + s_i Y_i)); if W: fuse next
//      layer matvec, write (10,n); else write z (rowmajor -> (n,10)). -------
__global__ __launch_bounds__(256) void k_ap(const float* __restrict__ A,
                                            const float* __restrict__ s,
                                            const float* __restrict__ Yt,
                                            const float* __restrict__ W,
                                            float* __restrict__ Ot, int n,
                                            int rowmajor) {
    const int i   = blockIdx.x;
    const int tid = threadIdx.x;
    float acc[GCNW];
    #pragma unroll
    for (int o = 0; o < GCNW; ++o) acc[o] = 0.f;
    const float4* a4 = (const float4*)(A + (size_t)i * n);
    const float4* s4 = (const float4*)s;
    for (int j4 = tid; j4 < n / 4; j4 += 256) {
        float4 a  = a4[j4];
        float4 sv = s4[j4];
        a.x *= sv.x; a.y *= sv.y; a.z *= sv.z; a.w *= sv.w;
        #pragma unroll
        for (int o = 0; o < GCNW; ++o) {
            float4 y = ((const float4*)(Yt + (size_t)o * n))[j4];
            acc[o] = fmaf(a.x, y.x, acc[o]);
            acc[o] = fmaf(a.y, y.y, acc[o]);
            acc[o] = fmaf(a.z, y.z, acc[o]);
            acc[o] = fmaf(a.w, y.w, acc[o]);
        }
    }
    #pragma unroll
    for (int o = 0; o < GCNW; ++o) {
        float v = acc[o];
        #pragma unroll
        for (int off = 32; off > 0; off >>= 1) v += __shfl_xor(v, off);
        acc[o] = v;
    }
    __shared__ float part[4][GCNW];
    __shared__ float zsh[GCNW];
    const int wv = tid >> 6, ln = tid & 63;
    if (ln == 0) {
        #pragma unroll
        for (int o = 0; o < GCNW; ++o) part[wv][o] = acc[o];
    }
    __syncthreads();
    if (tid < GCNW) {
        float dot = part[0][tid] + part[1][tid] + part[2][tid] + part[3][tid];
        float si  = s[i];
        float z   = selu_f(si * (dot + si * Yt[(size_t)tid * n + i]));
        if (W) zsh[tid] = z;
        else if (rowmajor) Ot[(size_t)i * GCNW + tid] = z;
        else               Ot[(size_t)tid * n + i]    = z;
    }
    if (W) {
        __syncthreads();
        if (tid < GCNW) {
            float d = 0.f;
            #pragma unroll
            for (int u = 0; u < GCNW; ++u) d = fmaf(zsh[u], W[tid * GCNW + u], d);
            Ot[(size_t)tid * n + i] = d;
        }
    }
}

// ---------------------------------------------------------------------------
// LSTM shared pieces. Gate-lane layout (per wave): quad u = lane>>2 (hidden
// unit), gt = lane&3 in {i,f,g,o}. Gate-input weights pre-scaled by -log2e
// (sig) / -2log2e (tanh); c carried UNSCALED. Dots in packed fp32. Cell tanh
// via continued-fraction rational (clamp 4.6, max err ~8e-4) — removes one
// exp2 from the serial chain per stage.
// ---------------------------------------------------------------------------
struct SBV { v2f v[5]; };      // 10 broadcast values as 5 packed pairs

__device__ __forceinline__ SBV bc2(float x) {
    SBV r;
    #pragma unroll
    for (int j = 0; j < 5; ++j) {
        v2f p; p.x = rl(x, 8 * j); p.y = rl(x, 8 * j + 4);
        r.v[j] = p;
    }
    return r;
}

__device__ __forceinline__ SBV loadrow2(const float* __restrict__ p) {
    SBV r;
    #pragma unroll
    for (int j = 0; j < 5; ++j) { v2f t; t.x = p[2*j]; t.y = p[2*j+1]; r.v[j] = t; }
    return r;
}

__device__ __forceinline__ SBV ldsrow2(const float* p) {
    float4 a = ((const float4*)p)[0];
    float4 b = ((const float4*)p)[1];
    float2 c = *(const float2*)(p + 8);
    SBV r;
    r.v[0] = (v2f){a.x, a.y}; r.v[1] = (v2f){a.z, a.w};
    r.v[2] = (v2f){b.x, b.y}; r.v[3] = (v2f){b.z, b.w};
    r.v[4] = (v2f){c.x, c.y};
    return r;
}

// packed 10-term dot, seeded with init
__device__ __forceinline__ float dot10pk(const v2f (&w)[5], const SBV& x, float init) {
    v2f a0 = pkfma(w[0], x.v[0], (v2f){init, 0.f});
    v2f a1 = w[1] * x.v[1];
    a0 = pkfma(w[2], x.v[2], a0);
    a1 = pkfma(w[3], x.v[3], a1);
    a0 = pkfma(w[4], x.v[4], a0);
    a0 += a1;
    return a0.x + a0.y;
}

// rational tanh: t(10395+1260t^2+21t^4)/(10395+4725t^2+210t^4+t^6), |t|<=4.6
__device__ __forceinline__ float rtanh(float x) {
    float t  = fminf(fmaxf(x, -4.6f), 4.6f);      // v_med3
    float s  = t * t;
    float nu = t * fmaf(s, fmaf(s, 21.f, 1260.f), 10395.f);
    float s2 = s * s;
    float d1 = fmaf(s, 4725.f, 10395.f);
    float den = fmaf(s2, s + 210.f, d1);
    return nu * frcp(den);
}

// activation + cell update; gate sigmoid/tanh via exp2 (per-lane Qn: 0=sig,
// -1=g-tanh); cell tanh via rational. hn valid on gt==0 lanes.
__device__ __forceinline__ float act2(float acc, float& cS, float Qn) {
    float e  = fexp2(acc);
    float r  = frcp(1.f + e);
    float tg = fmaf(Qn, e, 1.f);
    float av = tg * r;                       // sig(a) or tanh(a) (unscaled)
    float fv = qb<1>(av), gv = qb<2>(av), ov = qb<3>(av);
    float cn = fmaf(fv, cS, av * gv);        // true c, valid on gt==0
    cS = cn;
    return ov * rtanh(cn);                   // hn = ov*tanh(c)
}

// ---- k_enc: waves 0-5 = (layer,dir); wave 6 = global->LDS staging ----------
__global__ __launch_bounds__(448, 1) void k_enc(
    const float* __restrict__ Hr,    // (n,10) encode inputs, row-major
    const float* __restrict__ W_ih, const float* __restrict__ W_hh,
    const float* __restrict__ b_ih, const float* __restrict__ b_hh,
    const float* __restrict__ h0,   const float* __restrict__ c0,
    float* __restrict__ hand,        // out: [l*20+slot]=h_last, [l*20+10+slot]=c
    int n)
{
    __shared__ __align__(16) float bufI[2][CHK * CROW];  // H input
    __shared__ __align__(16) float buf0[2][CHK * CROW];  // layer0 -> layer1
    __shared__ __align__(16) float buf1[2][CHK * CROW];  // layer1 -> layer2

    const int  lane = threadIdx.x & 63;
    const int  wid  = threadIdx.x >> 6;        // 0..5 = (layer,dir), 6 = staging
    const bool comp = wid < 6;
    const int  l    = comp ? (wid >> 1) : 0;
    const int  d    = comp ? (wid & 1) : 0;
    const int  ul   = lane >> 2, gt = lane & 3;
    const bool actl = comp && (ul < 5);        // 20 gate lanes per dir-wave
    const bool wl   = actl && (gt == 0);
    const int  ulc  = (ul < 5) ? ul : 0;
    const int  row  = gt * 5 + ulc;            // torch gate order i,f,g,o
    const bool isg  = (gt == 2);
    const float c2e = isg ? (-2.f * LOG2E) : (-LOG2E);
    const float Qn  = isg ? -1.f : 0.f;

    const int k = 2 * l + d;
    v2f wih[5];
    v2f wh01, wh23; float wh4;
    float bias, cS;
    #pragma unroll
    for (int j = 0; j < 5; ++j) {
        v2f t;
        t.x = actl ? c2e * W_ih[(k * 20 + row) * 10 + 2*j]     : 0.f;
        t.y = actl ? c2e * W_ih[(k * 20 + row) * 10 + 2*j + 1] : 0.f;
        wih[j] = t;
    }
    {
        float w0 = actl ? c2e * W_hh[(k * 20 + row) * 5 + 0] : 0.f;
        float w1 = actl ? c2e * W_hh[(k * 20 + row) * 5 + 1] : 0.f;
        float w2 = actl ? c2e * W_hh[(k * 20 + row) * 5 + 2] : 0.f;
        float w3 = actl ? c2e * W_hh[(k * 20 + row) * 5 + 3] : 0.f;
        wh4     = actl ? c2e * W_hh[(k * 20 + row) * 5 + 4] : 0.f;
        wh01 = (v2f){w0, w1}; wh23 = (v2f){w2, w3};
    }
    bias = actl ? c2e * (b_ih[k * 20 + row] + b_hh[k * 20 + row]) : 0.f;
    cS   = actl ? c0[k * 5 + ulc] : 0.f;       // UNSCALED c

    v2f h01, h23; float h4;
    {
        float hi = actl ? h0[k * 5 + ulc] : 0.f;
        h01 = (v2f){rl(hi, 0),  rl(hi, 4)};
        h23 = (v2f){rl(hi, 8),  rl(hi, 12)};
        h4  = rl(hi, 16);
    }
    float hl = 0.f;

    // staging: wave 6, chunk q -> bufI[q&1]; lane covers rows 4*lane..4*lane+3
    auto stage_in = [&](int q) {
        const float2* src = (const float2*)(Hr + (size_t)(q * CHK + 4 * lane) * GCNW);
        float* d0 = bufI[q & 1] + (4 * lane) * CROW;
        #pragma unroll
        for (int rr = 0; rr < 4; ++rr) {
            float2 a0 = src[5*rr+0], a1 = src[5*rr+1], a2 = src[5*rr+2],
                   a3 = src[5*rr+3], a4 = src[5*rr+4];
            float2* dd = (float2*)(d0 + rr * CROW);
            dd[0]=a0; dd[1]=a1; dd[2]=a2; dd[3]=a3; dd[4]=a4;
        }
    };

    if (wid == 6) stage_in(0);
    __syncthreads();

    const int NCH = n / CHK;
    #pragma unroll 1
    for (int p = 0; p < NCH + 2; ++p) {
        if (wid == 6) {
            if (p + 1 < NCH) stage_in(p + 1);
        } else {
            const int ck = p - l;
            if (ck >= 0 && ck < NCH) {
                const float* rb = (l == 0) ? bufI[ck & 1]
                                 : (l == 1) ? buf0[ck & 1] : buf1[ck & 1];
                float* wb = (l == 0) ? buf0[ck & 1]
                           : (l == 1) ? buf1[ck & 1] : nullptr;
                SBV x0 = ldsrow2(rb);
                SBV x1 = ldsrow2(rb + CROW);
                float xd  = dot10pk(wih, x0, bias);
                float xd1 = dot10pk(wih, x1, bias);
                #pragma unroll 2
                for (int tt = 0; tt < CHK; ++tt) {
                    const int tp = (tt + 2 < CHK) ? tt + 2 : CHK - 1;
                    SBV x2 = ldsrow2(rb + tp * CROW);            // 2-deep prefetch
                    // chain: packed 5-term h-dot + activation
                    v2f a = pkfma(wh01, h01, (v2f){xd, 0.f});
                    a = pkfma(wh23, h23, a);
                    float acc = fmaf(wh4, h4, a.x + a.y);
                    float nh  = act2(acc, cS, Qn);
                    h01 = (v2f){rl(nh, 0), rl(nh, 4)};
                    h23 = (v2f){rl(nh, 8), rl(nh, 12)};
                    h4  = rl(nh, 16);
                    hl = nh;
                    if (wb && wl) wb[tt * CROW + d * 5 + ulc] = nh;
                    xd  = xd1;
                    xd1 = dot10pk(wih, x2, bias);                // off-chain
                }
            }
        }
        __syncthreads();
    }
    if (wl) { hand[l * 20 + d * 5 + ulc] = hl; hand[l * 20 + 10 + d * 5 + ulc] = cS; }
}

// ---- k_dec: wave 0 = serial recurrence (h2 -> LDS ring); wave 1 = head ----
__global__ __launch_bounds__(128, 1) void k_dec(
    const float* __restrict__ W_ih, const float* __restrict__ W_hh,
    const float* __restrict__ b_ih, const float* __restrict__ b_hh,
    const float* __restrict__ hand,  // from k_enc
    const float* __restrict__ tok,
    const float* __restrict__ Wo,   const float* __restrict__ bo,
    float* __restrict__ out, int n)
{
    __shared__ float ring[128 * GCNW];         // 128-step double buffer of h2

    const int  lane = threadIdx.x & 63;
    const int  wv   = threadIdx.x >> 6;        // 0 = recurrence, 1 = head
    const int  ul   = lane >> 2, gt = lane & 3;
    const bool actl = ul < GCNW;
    const bool st   = actl && (gt == 0);
    const int  ulc  = actl ? ul : 0;
    const int  dd   = ulc / 5, un = ulc % 5;
    const int  row  = gt * 5 + un;
    const bool isg  = (gt == 2);
    const float c2e = isg ? (-2.f * LOG2E) : (-LOG2E);
    const float Qn  = isg ? -1.f : 0.f;

    v2f wih[3][5], whh[3][5];
    float bias[3], cS[3];
    #pragma unroll
    for (int l = 0; l < 3; ++l) {
        const int k = 2 * l + dd;
        #pragma unroll
        for (int j = 0; j < 5; ++j) {
            v2f t;
            t.x = actl ? c2e * W_ih[(k * 20 + row) * 10 + 2*j]     : 0.f;
            t.y = actl ? c2e * W_ih[(k * 20 + row) * 10 + 2*j + 1] : 0.f;
            wih[l][j] = t;
            float z0 = 0.f, z1 = 0.f;
            if (actl && ((2*j)   / 5) == dd) z0 = c2e * W_hh[(k * 20 + row) * 5 + (2*j)   % 5];
            if (actl && ((2*j+1) / 5) == dd) z1 = c2e * W_hh[(k * 20 + row) * 5 + (2*j+1) % 5];
            whh[l][j] = (v2f){z0, z1};
        }
        bias[l] = actl ? c2e * (b_ih[k * 20 + row] + b_hh[k * 20 + row]) : 0.f;
        cS[l]   = actl ? hand[l * 20 + 10 + ulc] : 0.f;   // UNSCALED c
    }
    SBV B0 = bc2(actl ? hand[0 * 20 + ulc] : 0.f);
    SBV B1 = bc2(actl ? hand[1 * 20 + ulc] : 0.f);
    SBV B2 = bc2(actl ? hand[2 * 20 + ulc] : 0.f);

    float wo[GCNW];
    #pragma unroll
    for (int j = 0; j < GCNW; ++j) wo[j] = Wo[j];
    const float bo0 = bo[0];

    // hp pipeline: hp_l = bias_l + Whh_l . h_l  (off the serial chain)
    float hp0 = dot10pk(whh[0], B0, bias[0]);
    float hp1 = dot10pk(whh[1], B1, bias[1]);
    float hp2 = dot10pk(whh[2], B2, bias[2]);

    if (wv == 0) {            // peel step 0 (x = decode token)
        SBV X = loadrow2(tok);
        float n0 = act2(dot10pk(wih[0], X, hp0), cS[0], Qn);
        B0 = bc2(n0);
        hp0 = dot10pk(whh[0], B0, bias[0]);
        float n1 = act2(dot10pk(wih[1], B0, hp1), cS[1], Qn);
        B1 = bc2(n1);
        hp1 = dot10pk(whh[1], B1, bias[1]);
        float n2 = act2(dot10pk(wih[2], B1, hp2), cS[2], Qn);
        B2 = bc2(n2);
        hp2 = dot10pk(whh[2], B2, bias[2]);
        if (st) ring[0 * GCNW + ulc] = n2;
    }

    const int NPH = n / 64;
    #pragma unroll 1
    for (int q = 0; q <= NPH; ++q) {
        if (wv == 0 && q < NPH) {
            const int tbase = q * 64;
            const int i0 = (q == 0) ? 1 : 0;       // step 0 already done
            #pragma unroll 2
            for (int i = i0; i < 64; ++i) {
                const int t = tbase + i;
                float n0 = act2(dot10pk(wih[0], B2, hp0), cS[0], Qn);
                B0 = bc2(n0);
                hp0 = dot10pk(whh[0], B0, bias[0]);           // off-chain
                float n1 = act2(dot10pk(wih[1], B0, hp1), cS[1], Qn);
                B1 = bc2(n1);
                hp1 = dot10pk(whh[1], B1, bias[1]);           // off-chain
                float n2 = act2(dot10pk(wih[2], B1, hp2), cS[2], Qn);
                B2 = bc2(n2);
                hp2 = dot10pk(whh[2], B2, bias[2]);           // off-chain
                if (st) ring[(t & 127) * GCNW + ulc] = n2;    // LDS, off-chain
            }
        } else if (wv == 1 && q > 0) {
            const int t = (q - 1) * 64 + lane;
            const float* h = &ring[(t & 127) * GCNW];
            float dsum = bo0;
            #pragma unroll
            for (int j = 0; j < GCNW; ++j) dsum = fmaf(wo[j], h[j], dsum);
            out[t] = frcp(1.f + fexp2(-LOG2E * dsum));
        }
        __syncthreads();
    }
}

extern "C" void kernel_launch(void* const* d_in, const int* in_sizes, int n_in,
                              void* d_out, int out_size, void* d_ws, size_t ws_size,
                              hipStream_t stream) {
    const float* A    = (const float*)d_in[0];
    const float* X    = (const float*)d_in[1];
    const float* W0   = (const float*)d_in[2];
    const float* W1   = (const float*)d_in[3];
    const float* W2   = (const float*)d_in[4];
    const float* W_ih = (const float*)d_in[5];
    const float* W_hh = (const float*)d_in[6];
    const float* b_ih = (const float*)d_in[7];
    const float* b_hh = (const float*)d_in[8];
    const float* h0   = (const float*)d_in[9];
    const float* c0   = (const float*)d_in[10];
    const float* tok  = (const float*)d_in[11];
    const float* Wo   = (const float*)d_in[12];
    const float* bo   = (const float*)d_in[13];
    float* out = (float*)d_out;

    const int n    = out_size;            // 4096
    const int feat = in_sizes[1] / n;     // 1024

    // workspace: s (n) | P0 (10n) | P1 (10n) | hand (64)
    float* s    = (float*)d_ws;
    float* P0   = s + n;
    float* P1   = P0 + (size_t)n * GCNW;
    float* hand = P1 + (size_t)n * GCNW;

    k_pre<<<2 * n, 256, 0, stream>>>(A, X, W0, s, P0, n, feat);        // s, Y0t
    k_ap <<<n,     256, 0, stream>>>(A, s, P0, W1,      P1, n, 0);     // Y1t (10,n)
    k_ap <<<n,     256, 0, stream>>>(A, s, P1, W2,      P0, n, 0);     // Y2t (10,n)
    k_ap <<<n,     256, 0, stream>>>(A, s, P0, nullptr, P1, n, 1);     // H  (n,10)
    k_enc<<<1, 448, 0, stream>>>(P1, W_ih, W_hh, b_ih, b_hh, h0, c0, hand, n);
    k_dec<<<1, 128, 0, stream>>>(W_ih, W_hh, b_ih, b_hh, hand, tok, Wo, bo, out, n);
}

// Round 12
// 2173.028 us; speedup vs baseline: 1.1162x; 1.1162x over previous
//
#include <hip/hip_runtime.h>
#include <math.h>

// ---------------------------------------------------------------------------
// GraphConvNetLSTM: GCN (3 layers, reassociated Ahat@(H@W.T)) + 3-layer bidir
// LSTM. k_enc: 7 waves (6 compute = layer x dir, 1 staging) pipelined over
// 128-step chunks via double-buffered LDS. k_dec: wave 0 = serial recurrence
// (h2 -> LDS ring), wave 1 = sigmoid head one phase behind. Packed fp32 dots
// (v_pk_fma_f32), exp2-based activations (R10's rational tanh regressed),
// s_setprio (compile-time constant) on the critical waves.
// ---------------------------------------------------------------------------

#define GCNW 10
#define LOG2E 1.4426950408889634f
#define CHK  128     // encode pipeline chunk (timesteps)
#define CROW 12      // padded LDS row stride (floats)

typedef float v2f __attribute__((ext_vector_type(2)));

__device__ __forceinline__ v2f pkfma(v2f a, v2f b, v2f c) {
#if __has_builtin(__builtin_elementwise_fma)
    return __builtin_elementwise_fma(a, b, c);
#else
    v2f r; r.x = fmaf(a.x, b.x, c.x); r.y = fmaf(a.y, b.y, c.y); return r;
#endif
}

template <int P>
__device__ __forceinline__ void setprio() {
#if __has_builtin(__builtin_amdgcn_s_setprio)
    __builtin_amdgcn_s_setprio(P);
#endif
}

__device__ __forceinline__ float rl(float v, int l) {
    return __int_as_float(__builtin_amdgcn_readlane(__float_as_int(v), l));
}
__device__ __forceinline__ float frcp(float x) { return __builtin_amdgcn_rcpf(x); }

#if __has_builtin(__builtin_amdgcn_exp2f)
__device__ __forceinline__ float fexp2(float x) { return __builtin_amdgcn_exp2f(x); }
#else
__device__ __forceinline__ float fexp2(float x) { return __expf(x * 0.6931471805599453f); }
#endif

template <int L>
__device__ __forceinline__ float qb(float v) {
    constexpr int ctrl = L | (L << 2) | (L << 4) | (L << 6);
    int r = __builtin_amdgcn_update_dpp(0, __float_as_int(v), ctrl, 0xF, 0xF, true);
    return __int_as_float(r);
}

__device__ __forceinline__ float selu_f(float x) {
    const float lam = 1.0507009873554805f;
    const float la  = 1.7580993408473766f;
    return x > 0.f ? lam * x : la * (__expf(x) - 1.f);
}

// ---- k_pre: blocks [0,n) rowsum->s ; blocks [n,2n) Y0t[o][i] = X[i]@W0.T ---
__global__ __launch_bounds__(256) void k_pre(const float* __restrict__ A,
                                             const float* __restrict__ X,
                                             const float* __restrict__ W0,
                                             float* __restrict__ s,
                                             float* __restrict__ Y0t,
                                             int n, int feat) {
    const int b   = blockIdx.x;
    const int tid = threadIdx.x;
    if (b < n) {
        __shared__ float red[256];
        const float4* row4 = (const float4*)(A + (size_t)b * n);
        float acc = 0.f;
        for (int j = tid; j < n / 4; j += 256) {
            float4 a = row4[j];
            acc += (a.x + a.y) + (a.z + a.w);
        }
        red[tid] = acc; __syncthreads();
        #pragma unroll
        for (int w = 128; w > 0; w >>= 1) {
            if (tid < w) red[tid] += red[tid + w];
            __syncthreads();
        }
        if (tid == 0) {
            float deg = red[0];
            s[b] = (deg > 0.f) ? rsqrtf(deg) : 0.f;
        }
    } else {
        const int i = b - n;
        float acc[GCNW];
        #pragma unroll
        for (int o = 0; o < GCNW; ++o) acc[o] = 0.f;
        const float* xr = X + (size_t)i * feat;
        for (int j = tid; j < feat; j += 256) {
            float xv = xr[j];
            #pragma unroll
            for (int o = 0; o < GCNW; ++o) acc[o] = fmaf(xv, W0[o * feat + j], acc[o]);
        }
        #pragma unroll
        for (int o = 0; o < GCNW; ++o) {
            float v = acc[o];
            #pragma unroll
            for (int off = 32; off > 0; off >>= 1) v += __shfl_xor(v, off);
            acc[o] = v;
        }
        __shared__ float part[4][GCNW];
        const int wv = tid >> 6, ln = tid & 63;
        if (ln == 0) {
            #pragma unroll
            for (int o = 0; o < GCNW; ++o) part[wv][o] = acc[o];
        }
        __syncthreads();
        if (tid < GCNW)
            Y0t[(size_t)tid * n + i] =
                part[0][tid] + part[1][tid] + part[2][tid] + part[3][tid];
    }
}

// ---- k_ap: z = selu(s_i*(sum_j A_ij s_j Y_j + s_i Y_i)); if W: fuse next
//      layer matvec, write (10,n); else write z (rowmajor -> (n,10)). -------
__global__ __launch_bounds__(256) void k_ap(const float* __restrict__ A,
                                            const float* __restrict__ s,
                                            const float* __restrict__ Yt,
                                            const float* __restrict__ W,
                                            float* __restrict__ Ot, int n,
                                            int rowmajor) {
    const int i   = blockIdx.x;
    const int tid = threadIdx.x;
    float acc[GCNW];
    #pragma unroll
    for (int o = 0; o < GCNW; ++o) acc[o] = 0.f;
    const float4* a4 = (const float4*)(A + (size_t)i * n);
    const float4* s4 = (const float4*)s;
    for (int j4 = tid; j4 < n / 4; j4 += 256) {
        float4 a  = a4[j4];
        float4 sv = s4[j4];
        a.x *= sv.x; a.y *= sv.y; a.z *= sv.z; a.w *= sv.w;
        #pragma unroll
        for (int o = 0; o < GCNW; ++o) {
            float4 y = ((const float4*)(Yt + (size_t)o * n))[j4];
            acc[o] = fmaf(a.x, y.x, acc[o]);
            acc[o] = fmaf(a.y, y.y, acc[o]);
            acc[o] = fmaf(a.z, y.z, acc[o]);
            acc[o] = fmaf(a.w, y.w, acc[o]);
        }
    }
    #pragma unroll
    for (int o = 0; o < GCNW; ++o) {
        float v = acc[o];
        #pragma unroll
        for (int off = 32; off > 0; off >>= 1) v += __shfl_xor(v, off);
        acc[o] = v;
    }
    __shared__ float part[4][GCNW];
    __shared__ float zsh[GCNW];
    const int wv = tid >> 6, ln = tid & 63;
    if (ln == 0) {
        #pragma unroll
        for (int o = 0; o < GCNW; ++o) part[wv][o] = acc[o];
    }
    __syncthreads();
    if (tid < GCNW) {
        float dot = part[0][tid] + part[1][tid] + part[2][tid] + part[3][tid];
        float si  = s[i];
        float z   = selu_f(si * (dot + si * Yt[(size_t)tid * n + i]));
        if (W) zsh[tid] = z;
        else if (rowmajor) Ot[(size_t)i * GCNW + tid] = z;
        else               Ot[(size_t)tid * n + i]    = z;
    }
    if (W) {
        __syncthreads();
        if (tid < GCNW) {
            float d = 0.f;
            #pragma unroll
            for (int u = 0; u < GCNW; ++u) d = fmaf(zsh[u], W[tid * GCNW + u], d);
            Ot[(size_t)tid * n + i] = d;
        }
    }
}

// ---------------------------------------------------------------------------
// LSTM shared pieces. Gate-lane layout (per wave): quad u = lane>>2 (hidden
// unit), gt = lane&3 in {i,f,g,o}. Weights pre-scaled by -log2e (sig) /
// -2log2e (tanh); c carried pre-scaled by -2log2e. Dots in packed fp32.
// ---------------------------------------------------------------------------
struct SBV { v2f v[5]; };      // 10 broadcast values as 5 packed pairs

__device__ __forceinline__ SBV bc2(float x) {
    SBV r;
    #pragma unroll
    for (int j = 0; j < 5; ++j) {
        v2f p; p.x = rl(x, 8 * j); p.y = rl(x, 8 * j + 4);
        r.v[j] = p;
    }
    return r;
}

__device__ __forceinline__ SBV loadrow2(const float* __restrict__ p) {
    SBV r;
    #pragma unroll
    for (int j = 0; j < 5; ++j) { v2f t; t.x = p[2*j]; t.y = p[2*j+1]; r.v[j] = t; }
    return r;
}

__device__ __forceinline__ SBV ldsrow2(const float* p) {
    float4 a = ((const float4*)p)[0];
    float4 b = ((const float4*)p)[1];
    float2 c = *(const float2*)(p + 8);
    SBV r;
    r.v[0] = (v2f){a.x, a.y}; r.v[1] = (v2f){a.z, a.w};
    r.v[2] = (v2f){b.x, b.y}; r.v[3] = (v2f){b.z, b.w};
    r.v[4] = (v2f){c.x, c.y};
    return r;
}

// packed 10-term dot, seeded with init
__device__ __forceinline__ float dot10pk(const v2f (&w)[5], const SBV& x, float init) {
    v2f a0 = pkfma(w[0], x.v[0], (v2f){init, 0.f});
    v2f a1 = w[1] * x.v[1];
    a0 = pkfma(w[2], x.v[2], a0);
    a1 = pkfma(w[3], x.v[3], a1);
    a0 = pkfma(w[4], x.v[4], a0);
    a0 += a1;
    return a0.x + a0.y;
}

// activation + cell update from pre-scaled preactivation; hn on gt==0 lanes
__device__ __forceinline__ float act2(float acc, float& cS, float P, float Qn) {
    float e  = fexp2(acc);
    float r  = frcp(1.f + e);
    float tg = fmaf(Qn, e, P);
    float av = tg * r;                       // sig(a) or -2log2e*tanh(a)
    float fv = qb<1>(av), gv = qb<2>(av), ov = qb<3>(av);
    float cn = fmaf(fv, cS, av * gv);
    cS = cn;
    float e2 = fexp2(cn);
    float r2 = frcp(1.f + e2);
    return fmaf(-ov, e2, ov) * r2;           // hn = ov*tanh(c_true)
}

// ---- k_enc: waves 0-5 = (layer,dir); wave 6 = global->LDS staging ----------
__global__ __launch_bounds__(448, 1) void k_enc(
    const float* __restrict__ Hr,    // (n,10) encode inputs, row-major
    const float* __restrict__ W_ih, const float* __restrict__ W_hh,
    const float* __restrict__ b_ih, const float* __restrict__ b_hh,
    const float* __restrict__ h0,   const float* __restrict__ c0,
    float* __restrict__ hand,        // out: [l*20+slot]=h_last, [l*20+10+slot]=cS
    int n)
{
    __shared__ __align__(16) float bufI[2][CHK * CROW];  // H input
    __shared__ __align__(16) float buf0[2][CHK * CROW];  // layer0 -> layer1
    __shared__ __align__(16) float buf1[2][CHK * CROW];  // layer1 -> layer2

    const int  lane = threadIdx.x & 63;
    const int  wid  = threadIdx.x >> 6;        // 0..5 = (layer,dir), 6 = staging
    const bool comp = wid < 6;
    const int  l    = comp ? (wid >> 1) : 0;
    const int  d    = comp ? (wid & 1) : 0;
    const int  ul   = lane >> 2, gt = lane & 3;
    const bool actl = comp && (ul < 5);        // 20 gate lanes per dir-wave
    const bool wl   = actl && (gt == 0);
    const int  ulc  = (ul < 5) ? ul : 0;
    const int  row  = gt * 5 + ulc;            // torch gate order i,f,g,o
    const bool isg  = (gt == 2);
    const float c2e = isg ? (-2.f * LOG2E) : (-LOG2E);
    const float P   = isg ? (-2.f * LOG2E) : 1.f;
    const float Qn  = isg ? ( 2.f * LOG2E) : 0.f;

    if (comp) setprio<1>();                    // compute waves over staging

    const int k = 2 * l + d;
    v2f wih[5];
    v2f wh01, wh23; float wh4;
    float bias, cS;
    #pragma unroll
    for (int j = 0; j < 5; ++j) {
        v2f t;
        t.x = actl ? c2e * W_ih[(k * 20 + row) * 10 + 2*j]     : 0.f;
        t.y = actl ? c2e * W_ih[(k * 20 + row) * 10 + 2*j + 1] : 0.f;
        wih[j] = t;
    }
    {
        float w0 = actl ? c2e * W_hh[(k * 20 + row) * 5 + 0] : 0.f;
        float w1 = actl ? c2e * W_hh[(k * 20 + row) * 5 + 1] : 0.f;
        float w2 = actl ? c2e * W_hh[(k * 20 + row) * 5 + 2] : 0.f;
        float w3 = actl ? c2e * W_hh[(k * 20 + row) * 5 + 3] : 0.f;
        wh4     = actl ? c2e * W_hh[(k * 20 + row) * 5 + 4] : 0.f;
        wh01 = (v2f){w0, w1}; wh23 = (v2f){w2, w3};
    }
    bias = actl ? c2e * (b_ih[k * 20 + row] + b_hh[k * 20 + row]) : 0.f;
    cS   = actl ? (-2.f * LOG2E) * c0[k * 5 + ulc] : 0.f;

    v2f h01, h23; float h4;
    {
        float hi = actl ? h0[k * 5 + ulc] : 0.f;
        h01 = (v2f){rl(hi, 0),  rl(hi, 4)};
        h23 = (v2f){rl(hi, 8),  rl(hi, 12)};
        h4  = rl(hi, 16);
    }
    float hl = 0.f;

    // staging: wave 6, chunk q -> bufI[q&1]; lane covers rows 2*lane,2*lane+1
    auto stage_in = [&](int q) {
        const float2* src = (const float2*)(Hr + (size_t)(q * CHK + 2 * lane) * GCNW);
        float* d0 = bufI[q & 1] + (2 * lane) * CROW;
        float* d1 = d0 + CROW;
        float2 t0 = src[0], t1 = src[1], t2 = src[2], t3 = src[3], t4 = src[4];
        float2 u0 = src[5], u1 = src[6], u2 = src[7], u3 = src[8], u4 = src[9];
        ((float2*)d0)[0] = t0; ((float2*)d0)[1] = t1; ((float2*)d0)[2] = t2;
        ((float2*)d0)[3] = t3; ((float2*)d0)[4] = t4;
        ((float2*)d1)[0] = u0; ((float2*)d1)[1] = u1; ((float2*)d1)[2] = u2;
        ((float2*)d1)[3] = u3; ((float2*)d1)[4] = u4;
    };

    if (wid == 6) stage_in(0);
    __syncthreads();

    const int NCH = n / CHK;
    #pragma unroll 1
    for (int p = 0; p < NCH + 2; ++p) {
        if (wid == 6) {
            if (p + 1 < NCH) stage_in(p + 1);
        } else {
            const int ck = p - l;
            if (ck >= 0 && ck < NCH) {
                const float* rb = (l == 0) ? bufI[ck & 1]
                                 : (l == 1) ? buf0[ck & 1] : buf1[ck & 1];
                float* wb = (l == 0) ? buf0[ck & 1]
                           : (l == 1) ? buf1[ck & 1] : nullptr;
                SBV x0 = ldsrow2(rb);
                SBV x1 = ldsrow2(rb + CROW);
                float xd  = dot10pk(wih, x0, bias);
                float xd1 = dot10pk(wih, x1, bias);
                #pragma unroll 2
                for (int tt = 0; tt < CHK; ++tt) {
                    const int tp = (tt + 2 < CHK) ? tt + 2 : CHK - 1;
                    SBV x2 = ldsrow2(rb + tp * CROW);            // 2-deep prefetch
                    // chain: packed 5-term h-dot + activation
                    v2f a = pkfma(wh01, h01, (v2f){xd, 0.f});
                    a = pkfma(wh23, h23, a);
                    float acc = fmaf(wh4, h4, a.x + a.y);
                    float nh  = act2(acc, cS, P, Qn);
                    h01 = (v2f){rl(nh, 0), rl(nh, 4)};
                    h23 = (v2f){rl(nh, 8), rl(nh, 12)};
                    h4  = rl(nh, 16);
                    hl = nh;
                    if (wb && wl) wb[tt * CROW + d * 5 + ulc] = nh;
                    xd  = xd1;
                    xd1 = dot10pk(wih, x2, bias);                // off-chain
                }
            }
        }
        __syncthreads();
    }
    if (wl) { hand[l * 20 + d * 5 + ulc] = hl; hand[l * 20 + 10 + d * 5 + ulc] = cS; }
}

// ---- k_dec: wave 0 = serial recurrence (h2 -> LDS ring); wave 1 = head ----
__global__ __launch_bounds__(128, 1) void k_dec(
    const float* __restrict__ W_ih, const float* __restrict__ W_hh,
    const float* __restrict__ b_ih, const float* __restrict__ b_hh,
    const float* __restrict__ hand,  // from k_enc
    const float* __restrict__ tok,
    const float* __restrict__ Wo,   const float* __restrict__ bo,
    float* __restrict__ out, int n)
{
    __shared__ float ring[128 * GCNW];         // 128-step double buffer of h2

    const int  lane = threadIdx.x & 63;
    const int  wv   = threadIdx.x >> 6;        // 0 = recurrence, 1 = head
    const int  ul   = lane >> 2, gt = lane & 3;
    const bool actl = ul < GCNW;
    const bool st   = actl && (gt == 0);
    const int  ulc  = actl ? ul : 0;
    const int  dd   = ulc / 5, un = ulc % 5;
    const int  row  = gt * 5 + un;
    const bool isg  = (gt == 2);
    const float c2e = isg ? (-2.f * LOG2E) : (-LOG2E);
    const float P   = isg ? (-2.f * LOG2E) : 1.f;
    const float Qn  = isg ? ( 2.f * LOG2E) : 0.f;

    if (wv == 0) setprio<3>();                 // critical recurrence wave

    v2f wih[3][5], whh[3][5];
    float bias[3], cS[3];
    #pragma unroll
    for (int l = 0; l < 3; ++l) {
        const int k = 2 * l + dd;
        #pragma unroll
        for (int j = 0; j < 5; ++j) {
            v2f t;
            t.x = actl ? c2e * W_ih[(k * 20 + row) * 10 + 2*j]     : 0.f;
            t.y = actl ? c2e * W_ih[(k * 20 + row) * 10 + 2*j + 1] : 0.f;
            wih[l][j] = t;
            float z0 = 0.f, z1 = 0.f;
            if (actl && ((2*j)   / 5) == dd) z0 = c2e * W_hh[(k * 20 + row) * 5 + (2*j)   % 5];
            if (actl && ((2*j+1) / 5) == dd) z1 = c2e * W_hh[(k * 20 + row) * 5 + (2*j+1) % 5];
            whh[l][j] = (v2f){z0, z1};
        }
        bias[l] = actl ? c2e * (b_ih[k * 20 + row] + b_hh[k * 20 + row]) : 0.f;
        cS[l]   = actl ? hand[l * 20 + 10 + ulc] : 0.f;
    }
    SBV B0 = bc2(actl ? hand[0 * 20 + ulc] : 0.f);
    SBV B1 = bc2(actl ? hand[1 * 20 + ulc] : 0.f);
    SBV B2 = bc2(actl ? hand[2 * 20 + ulc] : 0.f);

    float wo[GCNW];
    #pragma unroll
    for (int j = 0; j < GCNW; ++j) wo[j] = Wo[j];
    const float bo0 = bo[0];

    // hp pipeline: hp_l = bias_l + Whh_l . h_l  (off the serial chain)
    float hp0 = dot10pk(whh[0], B0, bias[0]);
    float hp1 = dot10pk(whh[1], B1, bias[1]);
    float hp2 = dot10pk(whh[2], B2, bias[2]);

    if (wv == 0) {            // peel step 0 (x = decode token)
        SBV X = loadrow2(tok);
        float n0 = act2(dot10pk(wih[0], X, hp0), cS[0], P, Qn);
        B0 = bc2(n0);
        hp0 = dot10pk(whh[0], B0, bias[0]);
        float n1 = act2(dot10pk(wih[1], B0, hp1), cS[1], P, Qn);
        B1 = bc2(n1);
        hp1 = dot10pk(whh[1], B1, bias[1]);
        float n2 = act2(dot10pk(wih[2], B1, hp2), cS[2], P, Qn);
        B2 = bc2(n2);
        hp2 = dot10pk(whh[2], B2, bias[2]);
        if (st) ring[0 * GCNW + ulc] = n2;
    }

    const int NPH = n / 64;
    #pragma unroll 1
    for (int q = 0; q <= NPH; ++q) {
        if (wv == 0 && q < NPH) {
            const int tbase = q * 64;
            const int i0 = (q == 0) ? 1 : 0;       // step 0 already done
            #pragma unroll 2
            for (int i = i0; i < 64; ++i) {
                const int t = tbase + i;
                float n0 = act2(dot10pk(wih[0], B2, hp0), cS[0], P, Qn);
                B0 = bc2(n0);
                hp0 = dot10pk(whh[0], B0, bias[0]);           // off-chain
                float n1 = act2(dot10pk(wih[1], B0, hp1), cS[1], P, Qn);
                B1 = bc2(n1);
                hp1 = dot10pk(whh[1], B1, bias[1]);           // off-chain
                float n2 = act2(dot10pk(wih[2], B1, hp2), cS[2], P, Qn);
                B2 = bc2(n2);
                hp2 = dot10pk(whh[2], B2, bias[2]);           // off-chain
                if (st) ring[(t & 127) * GCNW + ulc] = n2;    // LDS, off-chain
            }
        } else if (wv == 1 && q > 0) {
            const int t = (q - 1) * 64 + lane;
            const float* h = &ring[(t & 127) * GCNW];
            float dsum = bo0;
            #pragma unroll
            for (int j = 0; j < GCNW; ++j) dsum = fmaf(wo[j], h[j], dsum);
            out[t] = frcp(1.f + fexp2(-LOG2E * dsum));
        }
        __syncthreads();
    }
}

extern "C" void kernel_launch(void* const* d_in, const int* in_sizes, int n_in,
                              void* d_out, int out_size, void* d_ws, size_t ws_size,
                              hipStream_t stream) {
    const float* A    = (const float*)d_in[0];
    const float* X    = (const float*)d_in[1];
    const float* W0   = (const float*)d_in[2];
    const float* W1   = (const float*)d_in[3];
    const float* W2   = (const float*)d_in[4];
    const float* W_ih = (const float*)d_in[5];
    const float* W_hh = (const float*)d_in[6];
    const float* b_ih = (const float*)d_in[7];
    const float* b_hh = (const float*)d_in[8];
    const float* h0   = (const float*)d_in[9];
    const float* c0   = (const float*)d_in[10];
    const float* tok  = (const float*)d_in[11];
    const float* Wo   = (const float*)d_in[12];
    const float* bo   = (const float*)d_in[13];
    float* out = (float*)d_out;

    const int n    = out_size;            // 4096
    const int feat = in_sizes[1] / n;     // 1024

    // workspace: s (n) | P0 (10n) | P1 (10n) | hand (64)
    float* s    = (float*)d_ws;
    float* P0   = s + n;
    float* P1   = P0 + (size_t)n * GCNW;
    float* hand = P1 + (size_t)n * GCNW;

    k_pre<<<2 * n, 256, 0, stream>>>(A, X, W0, s, P0, n, feat);        // s, Y0t
    k_ap <<<n,     256, 0, stream>>>(A, s, P0, W1,      P1, n, 0);     // Y1t (10,n)
    k_ap <<<n,     256, 0, stream>>>(A, s, P1, W2,      P0, n, 0);     // Y2t (10,n)
    k_ap <<<n,     256, 0, stream>>>(A, s, P0, nullptr, P1, n, 1);     // H  (n,10)
    k_enc<<<1, 448, 0, stream>>>(P1, W_ih, W_hh, b_ih, b_hh, h0, c0, hand, n);
    k_dec<<<1, 128, 0, stream>>>(W_ih, W_hh, b_ih, b_hh, hand, tok, Wo, bo, out, n);
}